// Round 10
// baseline (247.265 us; speedup 1.0000x reference)
//
#include <hip/hip_runtime.h>
#include <math.h>

#define BDIM 512
#define EDIM 4096
#define KDIM 1024
#define MDIM 1024
#define LDIM 32
#define TOPK 4
#define EPSF 1e-12f

typedef __attribute__((ext_vector_type(8))) short short8;
typedef __attribute__((ext_vector_type(4))) float f32x4;

struct us4 { ushort x, y, z, w; };

__device__ inline ushort f2bf_rn(float x) {
    union { float f; unsigned u; } v; v.f = x;
    unsigned r = (v.u + 0x7FFF + ((v.u >> 16) & 1)) >> 16;
    return (ushort)r;
}
__device__ inline float bf2f(ushort h) {
    union { unsigned u; float f; } v; v.u = ((unsigned)h) << 16;
    return v.f;
}
// fp32x8 -> (hi, lo) bf16x8; identical bit pattern across all rounds.
__device__ inline void split8(const float4& v0, const float4& v1,
                              short8& h, short8& l)
{
    float f[8] = {v0.x, v0.y, v0.z, v0.w, v1.x, v1.y, v1.z, v1.w};
    #pragma unroll
    for (int e = 0; e < 8; ++e) {
        ushort hh = f2bf_rn(f[e]);
        h[e] = (short)hh;
        l[e] = (short)f2bf_rn(f[e] - bf2f(hh));
    }
}

// ---------------------------------------------------------------------------
// GEMM1: x_proj partials from fp32 x_query/W_proj, in-register hi/lo split,
// 64x128 tile, dbuf LDS, split-K=4 -> Cp1[z][512][1024]. (Frozen from R9.)
// ---------------------------------------------------------------------------
__global__ __launch_bounds__(256)
void gemm1_kernel(const float* __restrict__ A, const float* __restrict__ B,
                  float* __restrict__ Cp)
{
    __shared__ ushort ldsA[2][2][64][40];    // [buf][hi/lo][row][col]
    __shared__ ushort ldsB[2][2][128][40];

    const int t  = threadIdx.x;
    const int bn = blockIdx.x, bm = blockIdx.y, kz = blockIdx.z;
    const int srow = t >> 2, sg = t & 3;
    const int Kc = EDIM / 4;                 // 1024

    const size_t aoff  = (size_t)(bm * 64 + srow) * EDIM + kz * Kc + sg * 8;
    const size_t boff0 = (size_t)(bn * 128 + srow) * EDIM + kz * Kc + sg * 8;
    const size_t boff1 = (size_t)(bn * 128 + 64 + srow) * EDIM + kz * Kc + sg * 8;

    const int lane = t & 63, wid = t >> 6;
    const int wr = wid >> 1, wc = wid & 1;
    const int fr = lane & 15, fg = lane >> 4;

    f32x4 acc[2][4];
    #pragma unroll
    for (int i = 0; i < 2; ++i)
        #pragma unroll
        for (int j = 0; j < 4; ++j)
            acc[i][j] = (f32x4){0.f, 0.f, 0.f, 0.f};

    float4 a0 = *(const float4*)(A + aoff),  a1 = *(const float4*)(A + aoff + 4);
    float4 b00 = *(const float4*)(B + boff0), b01 = *(const float4*)(B + boff0 + 4);
    float4 b10 = *(const float4*)(B + boff1), b11 = *(const float4*)(B + boff1 + 4);

    {
        short8 hs, ls;
        split8(a0, a1, hs, ls);
        *(short8*)(&ldsA[0][0][srow][sg * 8]) = hs;
        *(short8*)(&ldsA[0][1][srow][sg * 8]) = ls;
        split8(b00, b01, hs, ls);
        *(short8*)(&ldsB[0][0][srow][sg * 8]) = hs;
        *(short8*)(&ldsB[0][1][srow][sg * 8]) = ls;
        split8(b10, b11, hs, ls);
        *(short8*)(&ldsB[0][0][64 + srow][sg * 8]) = hs;
        *(short8*)(&ldsB[0][1][64 + srow][sg * 8]) = ls;
    }

    int p = 0;
    for (int k0 = 0; k0 < Kc; k0 += 32) {
        const bool more = (k0 + 32 < Kc);
        if (more) {                          // issue next-chunk global loads
            a0  = *(const float4*)(A + aoff + k0 + 32);
            a1  = *(const float4*)(A + aoff + k0 + 36);
            b00 = *(const float4*)(B + boff0 + k0 + 32);
            b01 = *(const float4*)(B + boff0 + k0 + 36);
            b10 = *(const float4*)(B + boff1 + k0 + 32);
            b11 = *(const float4*)(B + boff1 + k0 + 36);
        }
        __syncthreads();                     // buf[p] writes visible

        short8 ah[2], al[2], bh[4], bl[4];
        #pragma unroll
        for (int i = 0; i < 2; ++i) {
            ah[i] = *(const short8*)(&ldsA[p][0][wr * 32 + i * 16 + fr][fg * 8]);
            al[i] = *(const short8*)(&ldsA[p][1][wr * 32 + i * 16 + fr][fg * 8]);
        }
        #pragma unroll
        for (int j = 0; j < 4; ++j) {
            bh[j] = *(const short8*)(&ldsB[p][0][wc * 64 + j * 16 + fr][fg * 8]);
            bl[j] = *(const short8*)(&ldsB[p][1][wc * 64 + j * 16 + fr][fg * 8]);
        }
        #pragma unroll
        for (int i = 0; i < 2; ++i)
            #pragma unroll
            for (int j = 0; j < 4; ++j) {
                acc[i][j] = __builtin_amdgcn_mfma_f32_16x16x32_bf16(ah[i], bh[j], acc[i][j], 0, 0, 0);
                acc[i][j] = __builtin_amdgcn_mfma_f32_16x16x32_bf16(ah[i], bl[j], acc[i][j], 0, 0, 0);
                acc[i][j] = __builtin_amdgcn_mfma_f32_16x16x32_bf16(al[i], bh[j], acc[i][j], 0, 0, 0);
            }

        if (more) {                          // split + write next chunk to buf[p^1]
            short8 hs, ls;
            split8(a0, a1, hs, ls);
            *(short8*)(&ldsA[p ^ 1][0][srow][sg * 8]) = hs;
            *(short8*)(&ldsA[p ^ 1][1][srow][sg * 8]) = ls;
            split8(b00, b01, hs, ls);
            *(short8*)(&ldsB[p ^ 1][0][srow][sg * 8]) = hs;
            *(short8*)(&ldsB[p ^ 1][1][srow][sg * 8]) = ls;
            split8(b10, b11, hs, ls);
            *(short8*)(&ldsB[p ^ 1][0][64 + srow][sg * 8]) = hs;
            *(short8*)(&ldsB[p ^ 1][1][64 + srow][sg * 8]) = ls;
        }
        p ^= 1;
    }

    float* Cz = Cp + (size_t)kz * BDIM * KDIM;
    #pragma unroll
    for (int i = 0; i < 2; ++i)
        #pragma unroll
        for (int j = 0; j < 4; ++j)
            #pragma unroll
            for (int q = 0; q < 4; ++q) {
                int orow = bm * 64 + wr * 32 + i * 16 + (lane >> 4) * 4 + q;
                int ocol = bn * 128 + wc * 64 + j * 16 + (lane & 15);
                Cz[(size_t)orow * KDIM + ocol] = acc[i][j][q];
            }
}

// ---------------------------------------------------------------------------
// Fused reductions: blocks [0,512) = reduce Cp1 partials + norm + split;
// blocks [512,1536) = kn per pkeys row. (Frozen from R9, bit-identical.)
// ---------------------------------------------------------------------------
__global__ __launch_bounds__(256)
void reduce_split_norm_kernel(const float* __restrict__ Cp,
                              const float* __restrict__ PK,
                              ushort* __restrict__ xh, ushort* __restrict__ xl,
                              float* __restrict__ xn, float* __restrict__ kn)
{
    const int blk = blockIdx.x, t = threadIdx.x;
    float sq;
    if (blk < BDIM) {
        const int b = blk;
        const int i = b * 256 + t;
        const int n4 = BDIM * KDIM / 4;

        float4 s = ((const float4*)Cp)[i];
        #pragma unroll
        for (int z = 1; z < 4; ++z) {
            float4 v = ((const float4*)Cp)[(size_t)z * n4 + i];
            s.x += v.x; s.y += v.y; s.z += v.z; s.w += v.w;
        }

        us4 h, l;
        h.x = f2bf_rn(s.x); l.x = f2bf_rn(s.x - bf2f(h.x));
        h.y = f2bf_rn(s.y); l.y = f2bf_rn(s.y - bf2f(h.y));
        h.z = f2bf_rn(s.z); l.z = f2bf_rn(s.z - bf2f(h.z));
        h.w = f2bf_rn(s.w); l.w = f2bf_rn(s.w - bf2f(h.w));
        ((us4*)xh)[i] = h;
        ((us4*)xl)[i] = l;

        sq = s.x * s.x + s.y * s.y + s.z * s.z + s.w * s.w;
    } else {
        const int m = blk - BDIM;
        float4 v = *(const float4*)(PK + (size_t)m * KDIM + t * 4);
        sq = v.x * v.x + v.y * v.y + v.z * v.z + v.w * v.w;
    }
    #pragma unroll
    for (int off = 32; off > 0; off >>= 1) sq += __shfl_down(sq, off, 64);
    __shared__ float wsum[4];
    const int lane = t & 63, wwid = t >> 6;
    if (lane == 0) wsum[wwid] = sq;
    __syncthreads();
    if (t == 0) {
        float r = sqrtf(wsum[0] + wsum[1] + wsum[2] + wsum[3]);
        if (blk < BDIM) xn[blk] = r; else kn[blk - BDIM] = r;
    }
}

// ---------------------------------------------------------------------------
// GEMM2 (sim partials): A pre-split, B = pkeys fp32 in-register split,
// 64x64 tile, dbuf LDS, split-K=2. (Frozen from R9, bit-identical.)
// ---------------------------------------------------------------------------
__global__ __launch_bounds__(256)
void gemm2_kernel(const ushort* __restrict__ Ah, const ushort* __restrict__ Al,
                  const float* __restrict__ PK, float* __restrict__ Cp)
{
    __shared__ ushort lds[2][4][64][40];     // [buf][Ah/Al/Bh/Bl][row][col]

    const int t  = threadIdx.x;
    const int bn = blockIdx.x, bm = blockIdx.y, kz = blockIdx.z;
    const int srow = t >> 2, sg = t & 3;
    const int Kc = KDIM / 2;                 // 512

    const size_t aoff = (size_t)(bm * 64 + srow) * KDIM + kz * Kc + sg * 8;
    const size_t boff = (size_t)(bn * 64 + srow) * KDIM + kz * Kc + sg * 8;

    const int lane = t & 63, wid = t >> 6;
    const int wr = wid >> 1, wc = wid & 1;
    const int fr = lane & 15, fg = lane >> 4;

    f32x4 acc[2][2];
    #pragma unroll
    for (int i = 0; i < 2; ++i)
        #pragma unroll
        for (int j = 0; j < 2; ++j)
            acc[i][j] = (f32x4){0.f, 0.f, 0.f, 0.f};

    short8 pA0 = *(const short8*)(Ah + aoff);
    short8 pA1 = *(const short8*)(Al + aoff);
    float4 pb0 = *(const float4*)(PK + boff);
    float4 pb1 = *(const float4*)(PK + boff + 4);

    {
        short8 hs, ls;
        split8(pb0, pb1, hs, ls);
        *(short8*)(&lds[0][0][srow][sg * 8]) = pA0;
        *(short8*)(&lds[0][1][srow][sg * 8]) = pA1;
        *(short8*)(&lds[0][2][srow][sg * 8]) = hs;
        *(short8*)(&lds[0][3][srow][sg * 8]) = ls;
    }

    int p = 0;
    for (int k0 = 0; k0 < Kc; k0 += 32) {
        const bool more = (k0 + 32 < Kc);
        if (more) {
            pA0 = *(const short8*)(Ah + aoff + k0 + 32);
            pA1 = *(const short8*)(Al + aoff + k0 + 32);
            pb0 = *(const float4*)(PK + boff + k0 + 32);
            pb1 = *(const float4*)(PK + boff + k0 + 36);
        }
        __syncthreads();

        short8 ah[2], al[2], bh[2], bl[2];
        #pragma unroll
        for (int i = 0; i < 2; ++i) {
            ah[i] = *(const short8*)(&lds[p][0][wr * 32 + i * 16 + fr][fg * 8]);
            al[i] = *(const short8*)(&lds[p][1][wr * 32 + i * 16 + fr][fg * 8]);
            bh[i] = *(const short8*)(&lds[p][2][wc * 32 + i * 16 + fr][fg * 8]);
            bl[i] = *(const short8*)(&lds[p][3][wc * 32 + i * 16 + fr][fg * 8]);
        }
        #pragma unroll
        for (int i = 0; i < 2; ++i)
            #pragma unroll
            for (int j = 0; j < 2; ++j) {
                acc[i][j] = __builtin_amdgcn_mfma_f32_16x16x32_bf16(ah[i], bh[j], acc[i][j], 0, 0, 0);
                acc[i][j] = __builtin_amdgcn_mfma_f32_16x16x32_bf16(ah[i], bl[j], acc[i][j], 0, 0, 0);
                acc[i][j] = __builtin_amdgcn_mfma_f32_16x16x32_bf16(al[i], bh[j], acc[i][j], 0, 0, 0);
            }

        if (more) {
            short8 hs, ls;
            split8(pb0, pb1, hs, ls);
            *(short8*)(&lds[p ^ 1][0][srow][sg * 8]) = pA0;
            *(short8*)(&lds[p ^ 1][1][srow][sg * 8]) = pA1;
            *(short8*)(&lds[p ^ 1][2][srow][sg * 8]) = hs;
            *(short8*)(&lds[p ^ 1][3][srow][sg * 8]) = ls;
        }
        p ^= 1;
    }

    float* Cz = Cp + (size_t)kz * BDIM * MDIM;
    #pragma unroll
    for (int i = 0; i < 2; ++i)
        #pragma unroll
        for (int j = 0; j < 2; ++j)
            #pragma unroll
            for (int q = 0; q < 4; ++q) {
                int orow = bm * 64 + wr * 32 + i * 16 + (lane >> 4) * 4 + q;
                int ocol = bn * 64 + wc * 32 + j * 16 + (lane & 15);
                Cz[(size_t)orow * MDIM + ocol] = acc[i][j][q];
            }
}

// ---------------------------------------------------------------------------
// Fused reduce(2 partials) + cosine scale + top-4 + softmax weights.
// (Frozen from R9, bit-identical.)
// ---------------------------------------------------------------------------
__device__ inline bool tk_better(float x, int ix, float y, int iy) {
    return (x > y) || (x == y && ix < iy);
}
__device__ inline void tk_insert(float (&v)[4], int (&id)[4], float x, int m) {
    if (tk_better(x, m, v[3], id[3])) {
        v[3] = x; id[3] = m;
        if (tk_better(v[3], id[3], v[2], id[2])) {
            float tv = v[2]; int ti = id[2]; v[2] = v[3]; id[2] = id[3]; v[3] = tv; id[3] = ti;
            if (tk_better(v[2], id[2], v[1], id[1])) {
                tv = v[1]; ti = id[1]; v[1] = v[2]; id[1] = id[2]; v[2] = tv; id[2] = ti;
                if (tk_better(v[1], id[1], v[0], id[0])) {
                    tv = v[0]; ti = id[0]; v[0] = v[1]; id[0] = id[1]; v[1] = tv; id[1] = ti;
                }
            }
        }
    }
}
__global__ __launch_bounds__(256)
void topk_scale_kernel(const float* __restrict__ Cp2, const float* __restrict__ xn,
                       const float* __restrict__ kn,
                       int* __restrict__ topi, float* __restrict__ topw)
{
    const int b = blockIdx.x, t = threadIdx.x;
    const int lane = t & 63, wid = t >> 6;
    const float sb = 1.f / fmaxf(xn[b], EPSF);
    const float* r0 = Cp2 + (size_t)b * MDIM;
    const float* r1 = Cp2 + (size_t)BDIM * MDIM + (size_t)b * MDIM;

    float v[4] = {-INFINITY, -INFINITY, -INFINITY, -INFINITY};
    int id[4] = {-1, -1, -1, -1};
    #pragma unroll
    for (int j = 0; j < MDIM / 256; ++j) {
        int m = wid * 256 + j * 64 + lane;
        float s = (r0[m] + r1[m]) * sb / fmaxf(kn[m], EPSF);
        tk_insert(v, id, s, m);
    }
    for (int off = 32; off >= 1; off >>= 1) {
        float pv[4]; int pi[4];
        #pragma unroll
        for (int q = 0; q < 4; ++q) {
            pv[q] = __shfl_xor(v[q], off, 64);
            pi[q] = __shfl_xor(id[q], off, 64);
        }
        #pragma unroll
        for (int q = 0; q < 4; ++q) tk_insert(v, id, pv[q], pi[q]);
    }

    __shared__ float sv[4][4];
    __shared__ int   si[4][4];
    if (lane == 0) {
        #pragma unroll
        for (int q = 0; q < 4; ++q) { sv[wid][q] = v[q]; si[wid][q] = id[q]; }
    }
    __syncthreads();
    if (t == 0) {
        float fv[4] = {-INFINITY, -INFINITY, -INFINITY, -INFINITY};
        int   fi[4] = {-1, -1, -1, -1};
        #pragma unroll
        for (int w = 0; w < 4; ++w)
            #pragma unroll
            for (int q = 0; q < 4; ++q)
                tk_insert(fv, fi, sv[w][q], si[w][q]);

        const float mx = fmaxf(fmaxf(fv[0], fv[1]), fmaxf(fv[2], fv[3]));
        const float e0 = expf(fv[0] - mx), e1 = expf(fv[1] - mx);
        const float e2 = expf(fv[2] - mx), e3 = expf(fv[3] - mx);
        const float inv = 1.f / (e0 + e1 + e2 + e3);
        topw[b * 4 + 0] = e0 * inv; topw[b * 4 + 1] = e1 * inv;
        topw[b * 4 + 2] = e2 * inv; topw[b * 4 + 3] = e3 * inv;
        #pragma unroll
        for (int q = 0; q < 4; ++q) topi[b * 4 + q] = fi[q];
    }
}

// ---------------------------------------------------------------------------
// NEW: counting sort of batches by their first selected prompt j0.
// Single block; bord is a permutation of 0..511 grouping batches that share
// j0. The permutation only changes gather-block SCHEDULING (each b still
// computes its own output rows) -> output bit-identical.
// ---------------------------------------------------------------------------
__global__ __launch_bounds__(256)
void sortb_kernel(const int* __restrict__ topi, int* __restrict__ bord)
{
    __shared__ int hist[MDIM];
    __shared__ int off[MDIM];
    __shared__ int keys[BDIM];
    const int t = threadIdx.x;
    for (int i = t; i < MDIM; i += 256) hist[i] = 0;
    __syncthreads();
    for (int b = t; b < BDIM; b += 256) {
        int k = topi[b * 4];                 // j0
        keys[b] = k;
        atomicAdd(&hist[k], 1);
    }
    __syncthreads();
    if (t == 0) {
        int acc = 0;
        for (int i = 0; i < MDIM; ++i) { off[i] = acc; acc += hist[i]; }
    }
    __syncthreads();
    for (int b = t; b < BDIM; b += 256) {
        int pos = atomicAdd(&off[keys[b]], 1);
        bord[pos] = b;
    }
}

// ---------------------------------------------------------------------------
// Gather + weighted sum. (l, rank)-major with rank -> b via the j0-sorted
// permutation: within each l-slice, blocks whose b's share j0 are adjacent,
// so their pm[(j0,l)] 16KB-row reads coincide in time (L2/L3 hit instead of
// a second HBM fetch). Non-temporal stores unchanged.
// ---------------------------------------------------------------------------
__global__ __launch_bounds__(256)
void gather_out_kernel(const float* __restrict__ pm, const int* __restrict__ topi,
                       const float* __restrict__ topw, const int* __restrict__ bord,
                       float* __restrict__ out)
{
    const int bl = blockIdx.x;
    const int rank = bl & (BDIM - 1);
    const int l = bl >> 9;
    const int b = bord[rank];

    const int j0 = topi[b * 4 + 0], j1 = topi[b * 4 + 1], j2 = topi[b * 4 + 2], j3 = topi[b * 4 + 3];
    const float w0 = topw[b * 4 + 0], w1 = topw[b * 4 + 1], w2 = topw[b * 4 + 2], w3 = topw[b * 4 + 3];

    const f32x4* p0 = (const f32x4*)(pm + ((size_t)j0 * LDIM + l) * EDIM);
    const f32x4* p1 = (const f32x4*)(pm + ((size_t)j1 * LDIM + l) * EDIM);
    const f32x4* p2 = (const f32x4*)(pm + ((size_t)j2 * LDIM + l) * EDIM);
    const f32x4* p3 = (const f32x4*)(pm + ((size_t)j3 * LDIM + l) * EDIM);
    f32x4* o = (f32x4*)(out + ((size_t)b * LDIM + l) * EDIM);

    #pragma unroll
    for (int it = 0; it < EDIM / 4 / 256; ++it) {
        const int c = it * 256 + threadIdx.x;
        f32x4 a = p0[c], bb = p1[c], cc = p2[c], dd = p3[c];
        f32x4 r = w0 * a + w1 * bb + w2 * cc + w3 * dd;
        __builtin_nontemporal_store(r, &o[c]);
    }
}

extern "C" void kernel_launch(void* const* d_in, const int* in_sizes, int n_in,
                              void* d_out, int out_size, void* d_ws, size_t ws_size,
                              hipStream_t stream)
{
    const float* x_query = (const float*)d_in[0];      // [B, E]
    const float* W_proj  = (const float*)d_in[1];      // [K, E]
    const float* pm      = (const float*)d_in[2];      // [M, L, E]
    const float* pkeys   = (const float*)d_in[3];      // [M, K]
    float* out = (float*)d_out;                        // [B, L, E]

    // workspace layout
    char* w = (char*)d_ws;
    ushort* xp_h = (ushort*)w; w += (size_t)BDIM * KDIM * 2;
    ushort* xp_l = (ushort*)w; w += (size_t)BDIM * KDIM * 2;
    float* Cp1  = (float*)w; w += (size_t)4 * BDIM * KDIM * 4;   // 8 MB
    float* Cp2  = (float*)w; w += (size_t)2 * BDIM * MDIM * 4;   // 4 MB
    float* xn   = (float*)w; w += BDIM * 4;
    float* kn   = (float*)w; w += MDIM * 4;
    float* topw = (float*)w; w += BDIM * TOPK * 4;
    int*   topi = (int*)w;   w += BDIM * TOPK * 4;
    int*   bord = (int*)w;   w += BDIM * 4;

    // 1. x_proj partials (fp32 inputs, in-register split, 64x128 dbuf, K=4)
    gemm1_kernel<<<dim3(KDIM / 128, BDIM / 64, 4), 256, 0, stream>>>(
        x_query, W_proj, Cp1);

    // 2. reduce + rownorm + split of x_proj  +  kn of pkeys rows
    reduce_split_norm_kernel<<<BDIM + MDIM, 256, 0, stream>>>(
        Cp1, pkeys, xp_h, xp_l, xn, kn);

    // 3. sim partials (A pre-split, B=pkeys fp32 in-register split, dbuf, K=2)
    gemm2_kernel<<<dim3(MDIM / 64, BDIM / 64, 2), 256, 0, stream>>>(
        xp_h, xp_l, pkeys, Cp2);

    // 4. reduce + cosine scale + top-4 + softmax weights (4 waves/row)
    topk_scale_kernel<<<BDIM, 256, 0, stream>>>(Cp2, xn, kn, topi, topw);

    // 5. sort batches by first selected prompt (scheduling-only permutation)
    sortb_kernel<<<1, 256, 0, stream>>>(topi, bord);

    // 6. gather + weighted sum -> out [512,32,4096], j0-clustered block order
    gather_out_kernel<<<BDIM * LDIM, 256, 0, stream>>>(pm, topi, topw, bord, out);
}

// Round 11
// 238.915 us; speedup vs baseline: 1.0349x; 1.0349x over previous
//
#include <hip/hip_runtime.h>
#include <math.h>

#define BDIM 512
#define EDIM 4096
#define KDIM 1024
#define MDIM 1024
#define LDIM 32
#define TOPK 4
#define EPSF 1e-12f

typedef __attribute__((ext_vector_type(8))) short short8;
typedef __attribute__((ext_vector_type(4))) float f32x4;

struct us4 { ushort x, y, z, w; };

__device__ inline ushort f2bf_rn(float x) {
    union { float f; unsigned u; } v; v.f = x;
    unsigned r = (v.u + 0x7FFF + ((v.u >> 16) & 1)) >> 16;
    return (ushort)r;
}
__device__ inline float bf2f(ushort h) {
    union { unsigned u; float f; } v; v.u = ((unsigned)h) << 16;
    return v.f;
}
// fp32x8 -> (hi, lo) bf16x8; identical bit pattern across all rounds.
__device__ inline void split8(const float4& v0, const float4& v1,
                              short8& h, short8& l)
{
    float f[8] = {v0.x, v0.y, v0.z, v0.w, v1.x, v1.y, v1.z, v1.w};
    #pragma unroll
    for (int e = 0; e < 8; ++e) {
        ushort hh = f2bf_rn(f[e]);
        h[e] = (short)hh;
        l[e] = (short)f2bf_rn(f[e] - bf2f(hh));
    }
}

// ---------------------------------------------------------------------------
// GEMM1: x_proj partials from fp32 x_query/W_proj, in-register hi/lo split,
// 64x128 tile, dbuf LDS, split-K=4 -> Cp1[z][512][1024].
// DEPTH-2 register pipeline: at 1 block/CU (120 KB LDS) there is no
// cross-block latency hiding, and depth-1 prefetch left the ~500-cycle
// global-load latency exposed (only ~120 MFMA cycles per step). Two named
// register sets X/Y with a manually 2x-unrolled k-loop issue each chunk's
// loads a FULL iteration before its ds_write consumes them.
// Scheduling-only change -> Cp1 bit-identical.
// ---------------------------------------------------------------------------
__global__ __launch_bounds__(256)
void gemm1_kernel(const float* __restrict__ A, const float* __restrict__ B,
                  float* __restrict__ Cp)
{
    __shared__ ushort ldsA[2][2][64][40];    // [buf][hi/lo][row][col]
    __shared__ ushort ldsB[2][2][128][40];

    const int t  = threadIdx.x;
    const int bn = blockIdx.x, bm = blockIdx.y, kz = blockIdx.z;
    const int srow = t >> 2, sg = t & 3;
    const int Kc = EDIM / 4;                 // 1024

    const size_t aoff  = (size_t)(bm * 64 + srow) * EDIM + kz * Kc + sg * 8;
    const size_t boff0 = (size_t)(bn * 128 + srow) * EDIM + kz * Kc + sg * 8;
    const size_t boff1 = (size_t)(bn * 128 + 64 + srow) * EDIM + kz * Kc + sg * 8;

    const int lane = t & 63, wid = t >> 6;
    const int wr = wid >> 1, wc = wid & 1;
    const int fr = lane & 15, fg = lane >> 4;

    f32x4 acc[2][4];
    #pragma unroll
    for (int i = 0; i < 2; ++i)
        #pragma unroll
        for (int j = 0; j < 4; ++j)
            acc[i][j] = (f32x4){0.f, 0.f, 0.f, 0.f};

    // register sets X (even chunks) and Y (odd chunks)
    float4 xa0, xa1, xb00, xb01, xb10, xb11;
    float4 ya0, ya1, yb00, yb01, yb10, yb11;

#define G1_LOAD(S, k)                                         \
    S##a0  = *(const float4*)(A + aoff  + (k));               \
    S##a1  = *(const float4*)(A + aoff  + (k) + 4);           \
    S##b00 = *(const float4*)(B + boff0 + (k));               \
    S##b01 = *(const float4*)(B + boff0 + (k) + 4);           \
    S##b10 = *(const float4*)(B + boff1 + (k));               \
    S##b11 = *(const float4*)(B + boff1 + (k) + 4);

#define G1_WRITE(S, buf)                                      \
    {                                                         \
        short8 hs_, ls_;                                      \
        split8(S##a0, S##a1, hs_, ls_);                       \
        *(short8*)(&ldsA[buf][0][srow][sg * 8]) = hs_;        \
        *(short8*)(&ldsA[buf][1][srow][sg * 8]) = ls_;        \
        split8(S##b00, S##b01, hs_, ls_);                     \
        *(short8*)(&ldsB[buf][0][srow][sg * 8]) = hs_;        \
        *(short8*)(&ldsB[buf][1][srow][sg * 8]) = ls_;        \
        split8(S##b10, S##b11, hs_, ls_);                     \
        *(short8*)(&ldsB[buf][0][64 + srow][sg * 8]) = hs_;   \
        *(short8*)(&ldsB[buf][1][64 + srow][sg * 8]) = ls_;   \
    }

#define G1_COMPUTE(buf)                                                              \
    {                                                                                \
        short8 ah[2], al[2], bh[4], bl[4];                                           \
        _Pragma("unroll")                                                            \
        for (int i = 0; i < 2; ++i) {                                                \
            ah[i] = *(const short8*)(&ldsA[buf][0][wr * 32 + i * 16 + fr][fg * 8]);  \
            al[i] = *(const short8*)(&ldsA[buf][1][wr * 32 + i * 16 + fr][fg * 8]);  \
        }                                                                            \
        _Pragma("unroll")                                                            \
        for (int j = 0; j < 4; ++j) {                                                \
            bh[j] = *(const short8*)(&ldsB[buf][0][wc * 64 + j * 16 + fr][fg * 8]);  \
            bl[j] = *(const short8*)(&ldsB[buf][1][wc * 64 + j * 16 + fr][fg * 8]);  \
        }                                                                            \
        _Pragma("unroll")                                                            \
        for (int i = 0; i < 2; ++i)                                                  \
            _Pragma("unroll")                                                        \
            for (int j = 0; j < 4; ++j) {                                            \
                acc[i][j] = __builtin_amdgcn_mfma_f32_16x16x32_bf16(ah[i], bh[j], acc[i][j], 0, 0, 0); \
                acc[i][j] = __builtin_amdgcn_mfma_f32_16x16x32_bf16(ah[i], bl[j], acc[i][j], 0, 0, 0); \
                acc[i][j] = __builtin_amdgcn_mfma_f32_16x16x32_bf16(al[i], bh[j], acc[i][j], 0, 0, 0); \
            }                                                                        \
    }

    // prologue: chunk0 -> X -> lds[0]; chunk1 -> Y   (Kc >= 64 always)
    G1_LOAD(x, 0)
    G1_WRITE(x, 0)
    G1_LOAD(y, 32)

    int p = 0;
    for (int k0 = 0; k0 < Kc; k0 += 64) {
        // even chunk k0: lds[p] holds it; X is free -> load chunk k0+64
        if (k0 + 64 < Kc) { G1_LOAD(x, k0 + 64) }
        __syncthreads();
        G1_COMPUTE(p)
        G1_WRITE(y, p ^ 1)                   // chunk k0+32 (always exists)
        p ^= 1;

        // odd chunk k0+32: lds[p] holds it; Y free -> load chunk k0+96
        if (k0 + 96 < Kc) { G1_LOAD(y, k0 + 96) }
        __syncthreads();
        G1_COMPUTE(p)
        if (k0 + 64 < Kc) { G1_WRITE(x, p ^ 1) }
        p ^= 1;
    }
#undef G1_LOAD
#undef G1_WRITE
#undef G1_COMPUTE

    float* Cz = Cp + (size_t)kz * BDIM * KDIM;
    #pragma unroll
    for (int i = 0; i < 2; ++i)
        #pragma unroll
        for (int j = 0; j < 4; ++j)
            #pragma unroll
            for (int q = 0; q < 4; ++q) {
                int orow = bm * 64 + wr * 32 + i * 16 + (lane >> 4) * 4 + q;
                int ocol = bn * 128 + wc * 64 + j * 16 + (lane & 15);
                Cz[(size_t)orow * KDIM + ocol] = acc[i][j][q];
            }
}

// ---------------------------------------------------------------------------
// Fused reductions: blocks [0,512) = reduce Cp1 partials + norm + split;
// blocks [512,1536) = kn per pkeys row. (Frozen, bit-identical.)
// ---------------------------------------------------------------------------
__global__ __launch_bounds__(256)
void reduce_split_norm_kernel(const float* __restrict__ Cp,
                              const float* __restrict__ PK,
                              ushort* __restrict__ xh, ushort* __restrict__ xl,
                              float* __restrict__ xn, float* __restrict__ kn)
{
    const int blk = blockIdx.x, t = threadIdx.x;
    float sq;
    if (blk < BDIM) {
        const int b = blk;
        const int i = b * 256 + t;
        const int n4 = BDIM * KDIM / 4;

        float4 s = ((const float4*)Cp)[i];
        #pragma unroll
        for (int z = 1; z < 4; ++z) {
            float4 v = ((const float4*)Cp)[(size_t)z * n4 + i];
            s.x += v.x; s.y += v.y; s.z += v.z; s.w += v.w;
        }

        us4 h, l;
        h.x = f2bf_rn(s.x); l.x = f2bf_rn(s.x - bf2f(h.x));
        h.y = f2bf_rn(s.y); l.y = f2bf_rn(s.y - bf2f(h.y));
        h.z = f2bf_rn(s.z); l.z = f2bf_rn(s.z - bf2f(h.z));
        h.w = f2bf_rn(s.w); l.w = f2bf_rn(s.w - bf2f(h.w));
        ((us4*)xh)[i] = h;
        ((us4*)xl)[i] = l;

        sq = s.x * s.x + s.y * s.y + s.z * s.z + s.w * s.w;
    } else {
        const int m = blk - BDIM;
        float4 v = *(const float4*)(PK + (size_t)m * KDIM + t * 4);
        sq = v.x * v.x + v.y * v.y + v.z * v.z + v.w * v.w;
    }
    #pragma unroll
    for (int off = 32; off > 0; off >>= 1) sq += __shfl_down(sq, off, 64);
    __shared__ float wsum[4];
    const int lane = t & 63, wwid = t >> 6;
    if (lane == 0) wsum[wwid] = sq;
    __syncthreads();
    if (t == 0) {
        float r = sqrtf(wsum[0] + wsum[1] + wsum[2] + wsum[3]);
        if (blk < BDIM) xn[blk] = r; else kn[blk - BDIM] = r;
    }
}

// ---------------------------------------------------------------------------
// GEMM2 (sim partials): A pre-split, B = pkeys fp32 in-register split,
// 64x64 tile, dbuf LDS, split-K=2. (Frozen, bit-identical; 2 blocks/CU
// already gives cross-block latency hiding.)
// ---------------------------------------------------------------------------
__global__ __launch_bounds__(256)
void gemm2_kernel(const ushort* __restrict__ Ah, const ushort* __restrict__ Al,
                  const float* __restrict__ PK, float* __restrict__ Cp)
{
    __shared__ ushort lds[2][4][64][40];     // [buf][Ah/Al/Bh/Bl][row][col]

    const int t  = threadIdx.x;
    const int bn = blockIdx.x, bm = blockIdx.y, kz = blockIdx.z;
    const int srow = t >> 2, sg = t & 3;
    const int Kc = KDIM / 2;                 // 512

    const size_t aoff = (size_t)(bm * 64 + srow) * KDIM + kz * Kc + sg * 8;
    const size_t boff = (size_t)(bn * 64 + srow) * KDIM + kz * Kc + sg * 8;

    const int lane = t & 63, wid = t >> 6;
    const int wr = wid >> 1, wc = wid & 1;
    const int fr = lane & 15, fg = lane >> 4;

    f32x4 acc[2][2];
    #pragma unroll
    for (int i = 0; i < 2; ++i)
        #pragma unroll
        for (int j = 0; j < 2; ++j)
            acc[i][j] = (f32x4){0.f, 0.f, 0.f, 0.f};

    short8 pA0 = *(const short8*)(Ah + aoff);
    short8 pA1 = *(const short8*)(Al + aoff);
    float4 pb0 = *(const float4*)(PK + boff);
    float4 pb1 = *(const float4*)(PK + boff + 4);

    {
        short8 hs, ls;
        split8(pb0, pb1, hs, ls);
        *(short8*)(&lds[0][0][srow][sg * 8]) = pA0;
        *(short8*)(&lds[0][1][srow][sg * 8]) = pA1;
        *(short8*)(&lds[0][2][srow][sg * 8]) = hs;
        *(short8*)(&lds[0][3][srow][sg * 8]) = ls;
    }

    int p = 0;
    for (int k0 = 0; k0 < Kc; k0 += 32) {
        const bool more = (k0 + 32 < Kc);
        if (more) {
            pA0 = *(const short8*)(Ah + aoff + k0 + 32);
            pA1 = *(const short8*)(Al + aoff + k0 + 32);
            pb0 = *(const float4*)(PK + boff + k0 + 32);
            pb1 = *(const float4*)(PK + boff + k0 + 36);
        }
        __syncthreads();

        short8 ah[2], al[2], bh[2], bl[2];
        #pragma unroll
        for (int i = 0; i < 2; ++i) {
            ah[i] = *(const short8*)(&lds[p][0][wr * 32 + i * 16 + fr][fg * 8]);
            al[i] = *(const short8*)(&lds[p][1][wr * 32 + i * 16 + fr][fg * 8]);
            bh[i] = *(const short8*)(&lds[p][2][wc * 32 + i * 16 + fr][fg * 8]);
            bl[i] = *(const short8*)(&lds[p][3][wc * 32 + i * 16 + fr][fg * 8]);
        }
        #pragma unroll
        for (int i = 0; i < 2; ++i)
            #pragma unroll
            for (int j = 0; j < 2; ++j) {
                acc[i][j] = __builtin_amdgcn_mfma_f32_16x16x32_bf16(ah[i], bh[j], acc[i][j], 0, 0, 0);
                acc[i][j] = __builtin_amdgcn_mfma_f32_16x16x32_bf16(ah[i], bl[j], acc[i][j], 0, 0, 0);
                acc[i][j] = __builtin_amdgcn_mfma_f32_16x16x32_bf16(al[i], bh[j], acc[i][j], 0, 0, 0);
            }

        if (more) {
            short8 hs, ls;
            split8(pb0, pb1, hs, ls);
            *(short8*)(&lds[p ^ 1][0][srow][sg * 8]) = pA0;
            *(short8*)(&lds[p ^ 1][1][srow][sg * 8]) = pA1;
            *(short8*)(&lds[p ^ 1][2][srow][sg * 8]) = hs;
            *(short8*)(&lds[p ^ 1][3][srow][sg * 8]) = ls;
        }
        p ^= 1;
    }

    float* Cz = Cp + (size_t)kz * BDIM * MDIM;
    #pragma unroll
    for (int i = 0; i < 2; ++i)
        #pragma unroll
        for (int j = 0; j < 2; ++j)
            #pragma unroll
            for (int q = 0; q < 4; ++q) {
                int orow = bm * 64 + wr * 32 + i * 16 + (lane >> 4) * 4 + q;
                int ocol = bn * 64 + wc * 32 + j * 16 + (lane & 15);
                Cz[(size_t)orow * MDIM + ocol] = acc[i][j][q];
            }
}

// ---------------------------------------------------------------------------
// Fused reduce(2 partials) + cosine scale + top-4 + softmax weights.
// (Frozen, bit-identical.)
// ---------------------------------------------------------------------------
__device__ inline bool tk_better(float x, int ix, float y, int iy) {
    return (x > y) || (x == y && ix < iy);
}
__device__ inline void tk_insert(float (&v)[4], int (&id)[4], float x, int m) {
    if (tk_better(x, m, v[3], id[3])) {
        v[3] = x; id[3] = m;
        if (tk_better(v[3], id[3], v[2], id[2])) {
            float tv = v[2]; int ti = id[2]; v[2] = v[3]; id[2] = id[3]; v[3] = tv; id[3] = ti;
            if (tk_better(v[2], id[2], v[1], id[1])) {
                tv = v[1]; ti = id[1]; v[1] = v[2]; id[1] = id[2]; v[2] = tv; id[2] = ti;
                if (tk_better(v[1], id[1], v[0], id[0])) {
                    tv = v[0]; ti = id[0]; v[0] = v[1]; id[0] = id[1]; v[1] = tv; id[1] = ti;
                }
            }
        }
    }
}
__global__ __launch_bounds__(256)
void topk_scale_kernel(const float* __restrict__ Cp2, const float* __restrict__ xn,
                       const float* __restrict__ kn,
                       int* __restrict__ topi, float* __restrict__ topw)
{
    const int b = blockIdx.x, t = threadIdx.x;
    const int lane = t & 63, wid = t >> 6;
    const float sb = 1.f / fmaxf(xn[b], EPSF);
    const float* r0 = Cp2 + (size_t)b * MDIM;
    const float* r1 = Cp2 + (size_t)BDIM * MDIM + (size_t)b * MDIM;

    float v[4] = {-INFINITY, -INFINITY, -INFINITY, -INFINITY};
    int id[4] = {-1, -1, -1, -1};
    #pragma unroll
    for (int j = 0; j < MDIM / 256; ++j) {
        int m = wid * 256 + j * 64 + lane;
        float s = (r0[m] + r1[m]) * sb / fmaxf(kn[m], EPSF);
        tk_insert(v, id, s, m);
    }
    for (int off = 32; off >= 1; off >>= 1) {
        float pv[4]; int pi[4];
        #pragma unroll
        for (int q = 0; q < 4; ++q) {
            pv[q] = __shfl_xor(v[q], off, 64);
            pi[q] = __shfl_xor(id[q], off, 64);
        }
        #pragma unroll
        for (int q = 0; q < 4; ++q) tk_insert(v, id, pv[q], pi[q]);
    }

    __shared__ float sv[4][4];
    __shared__ int   si[4][4];
    if (lane == 0) {
        #pragma unroll
        for (int q = 0; q < 4; ++q) { sv[wid][q] = v[q]; si[wid][q] = id[q]; }
    }
    __syncthreads();
    if (t == 0) {
        float fv[4] = {-INFINITY, -INFINITY, -INFINITY, -INFINITY};
        int   fi[4] = {-1, -1, -1, -1};
        #pragma unroll
        for (int w = 0; w < 4; ++w)
            #pragma unroll
            for (int q = 0; q < 4; ++q)
                tk_insert(fv, fi, sv[w][q], si[w][q]);

        const float mx = fmaxf(fmaxf(fv[0], fv[1]), fmaxf(fv[2], fv[3]));
        const float e0 = expf(fv[0] - mx), e1 = expf(fv[1] - mx);
        const float e2 = expf(fv[2] - mx), e3 = expf(fv[3] - mx);
        const float inv = 1.f / (e0 + e1 + e2 + e3);
        topw[b * 4 + 0] = e0 * inv; topw[b * 4 + 1] = e1 * inv;
        topw[b * 4 + 2] = e2 * inv; topw[b * 4 + 3] = e3 * inv;
        #pragma unroll
        for (int q = 0; q < 4; ++q) topi[b * 4 + q] = fi[q];
    }
}

// ---------------------------------------------------------------------------
// Gather + weighted sum. (l, b)-major + non-temporal stores; fully unrolled.
// (Reverted to the R9 form: the R10 j0-sort experiment showed block ordering
// is irrelevant — the whole l-slice is co-resident and L3 already absorbs
// the reuse at ~8 TB/s effective.)
// ---------------------------------------------------------------------------
__global__ __launch_bounds__(256)
void gather_out_kernel(const float* __restrict__ pm, const int* __restrict__ topi,
                       const float* __restrict__ topw, float* __restrict__ out)
{
    const int bl = blockIdx.x;
    const int b = bl & (BDIM - 1);   // (l, b)-major
    const int l = bl >> 9;

    const int j0 = topi[b * 4 + 0], j1 = topi[b * 4 + 1], j2 = topi[b * 4 + 2], j3 = topi[b * 4 + 3];
    const float w0 = topw[b * 4 + 0], w1 = topw[b * 4 + 1], w2 = topw[b * 4 + 2], w3 = topw[b * 4 + 3];

    const f32x4* p0 = (const f32x4*)(pm + ((size_t)j0 * LDIM + l) * EDIM);
    const f32x4* p1 = (const f32x4*)(pm + ((size_t)j1 * LDIM + l) * EDIM);
    const f32x4* p2 = (const f32x4*)(pm + ((size_t)j2 * LDIM + l) * EDIM);
    const f32x4* p3 = (const f32x4*)(pm + ((size_t)j3 * LDIM + l) * EDIM);
    f32x4* o = (f32x4*)(out + ((size_t)b * LDIM + l) * EDIM);

    #pragma unroll
    for (int it = 0; it < EDIM / 4 / 256; ++it) {
        const int c = it * 256 + threadIdx.x;
        f32x4 a = p0[c], bb = p1[c], cc = p2[c], dd = p3[c];
        f32x4 r = w0 * a + w1 * bb + w2 * cc + w3 * dd;
        __builtin_nontemporal_store(r, &o[c]);
    }
}

extern "C" void kernel_launch(void* const* d_in, const int* in_sizes, int n_in,
                              void* d_out, int out_size, void* d_ws, size_t ws_size,
                              hipStream_t stream)
{
    const float* x_query = (const float*)d_in[0];      // [B, E]
    const float* W_proj  = (const float*)d_in[1];      // [K, E]
    const float* pm      = (const float*)d_in[2];      // [M, L, E]
    const float* pkeys   = (const float*)d_in[3];      // [M, K]
    float* out = (float*)d_out;                        // [B, L, E]

    // workspace layout
    char* w = (char*)d_ws;
    ushort* xp_h = (ushort*)w; w += (size_t)BDIM * KDIM * 2;
    ushort* xp_l = (ushort*)w; w += (size_t)BDIM * KDIM * 2;
    float* Cp1  = (float*)w; w += (size_t)4 * BDIM * KDIM * 4;   // 8 MB
    float* Cp2  = (float*)w; w += (size_t)2 * BDIM * MDIM * 4;   // 4 MB
    float* xn   = (float*)w; w += BDIM * 4;
    float* kn   = (float*)w; w += MDIM * 4;
    float* topw = (float*)w; w += BDIM * TOPK * 4;
    int*   topi = (int*)w;   w += BDIM * TOPK * 4;

    // 1. x_proj partials (fp32 inputs, in-register split, depth-2 pipeline,
    //    64x128 dbuf, split-K=4)
    gemm1_kernel<<<dim3(KDIM / 128, BDIM / 64, 4), 256, 0, stream>>>(
        x_query, W_proj, Cp1);

    // 2. reduce + rownorm + split of x_proj  +  kn of pkeys rows
    reduce_split_norm_kernel<<<BDIM + MDIM, 256, 0, stream>>>(
        Cp1, pkeys, xp_h, xp_l, xn, kn);

    // 3. sim partials (A pre-split, B=pkeys fp32 in-register split, dbuf, K=2)
    gemm2_kernel<<<dim3(MDIM / 64, BDIM / 64, 2), 256, 0, stream>>>(
        xp_h, xp_l, pkeys, Cp2);

    // 4. reduce + cosine scale + top-4 + softmax weights (4 waves/row)
    topk_scale_kernel<<<BDIM, 256, 0, stream>>>(Cp2, xn, kn, topi, topw);

    // 5. gather + weighted sum -> out [512,32,4096]
    gather_out_kernel<<<BDIM * LDIM, 256, 0, stream>>>(pm, topi, topw, out);
}

// Round 12
// 234.982 us; speedup vs baseline: 1.0523x; 1.0167x over previous
//
#include <hip/hip_runtime.h>
#include <math.h>

#define BDIM 512
#define EDIM 4096
#define KDIM 1024
#define MDIM 1024
#define LDIM 32
#define TOPK 4
#define EPSF 1e-12f

typedef __attribute__((ext_vector_type(8))) short short8;
typedef __attribute__((ext_vector_type(4))) float f32x4;

struct us4 { ushort x, y, z, w; };

__device__ inline ushort f2bf_rn(float x) {
    union { float f; unsigned u; } v; v.f = x;
    unsigned r = (v.u + 0x7FFF + ((v.u >> 16) & 1)) >> 16;
    return (ushort)r;
}
__device__ inline float bf2f(ushort h) {
    union { unsigned u; float f; } v; v.u = ((unsigned)h) << 16;
    return v.f;
}
// fp32x8 -> (hi, lo) bf16x8; identical bit pattern across all rounds.
__device__ inline void split8(const float4& v0, const float4& v1,
                              short8& h, short8& l)
{
    float f[8] = {v0.x, v0.y, v0.z, v0.w, v1.x, v1.y, v1.z, v1.w};
    #pragma unroll
    for (int e = 0; e < 8; ++e) {
        ushort hh = f2bf_rn(f[e]);
        h[e] = (short)hh;
        l[e] = (short)f2bf_rn(f[e] - bf2f(hh));
    }
}

// ---------------------------------------------------------------------------
// GEMM1: x_proj partials from fp32 x_query/W_proj, in-register hi/lo split,
// 64x128 tile, dbuf LDS, depth-1 prefetch, split-K=4 -> Cp1[z][512][1024].
// (Exact R9 form — best measured. Depth-2 pipelining regressed: at 1
// wave/SIMD the hand-unrolled pipeline only displaced compiler scheduling.)
// ---------------------------------------------------------------------------
__global__ __launch_bounds__(256)
void gemm1_kernel(const float* __restrict__ A, const float* __restrict__ B,
                  float* __restrict__ Cp)
{
    __shared__ ushort ldsA[2][2][64][40];    // [buf][hi/lo][row][col]
    __shared__ ushort ldsB[2][2][128][40];

    const int t  = threadIdx.x;
    const int bn = blockIdx.x, bm = blockIdx.y, kz = blockIdx.z;
    const int srow = t >> 2, sg = t & 3;
    const int Kc = EDIM / 4;                 // 1024

    const size_t aoff  = (size_t)(bm * 64 + srow) * EDIM + kz * Kc + sg * 8;
    const size_t boff0 = (size_t)(bn * 128 + srow) * EDIM + kz * Kc + sg * 8;
    const size_t boff1 = (size_t)(bn * 128 + 64 + srow) * EDIM + kz * Kc + sg * 8;

    const int lane = t & 63, wid = t >> 6;
    const int wr = wid >> 1, wc = wid & 1;
    const int fr = lane & 15, fg = lane >> 4;

    f32x4 acc[2][4];
    #pragma unroll
    for (int i = 0; i < 2; ++i)
        #pragma unroll
        for (int j = 0; j < 4; ++j)
            acc[i][j] = (f32x4){0.f, 0.f, 0.f, 0.f};

    float4 a0 = *(const float4*)(A + aoff),  a1 = *(const float4*)(A + aoff + 4);
    float4 b00 = *(const float4*)(B + boff0), b01 = *(const float4*)(B + boff0 + 4);
    float4 b10 = *(const float4*)(B + boff1), b11 = *(const float4*)(B + boff1 + 4);

    {
        short8 hs, ls;
        split8(a0, a1, hs, ls);
        *(short8*)(&ldsA[0][0][srow][sg * 8]) = hs;
        *(short8*)(&ldsA[0][1][srow][sg * 8]) = ls;
        split8(b00, b01, hs, ls);
        *(short8*)(&ldsB[0][0][srow][sg * 8]) = hs;
        *(short8*)(&ldsB[0][1][srow][sg * 8]) = ls;
        split8(b10, b11, hs, ls);
        *(short8*)(&ldsB[0][0][64 + srow][sg * 8]) = hs;
        *(short8*)(&ldsB[0][1][64 + srow][sg * 8]) = ls;
    }

    int p = 0;
    for (int k0 = 0; k0 < Kc; k0 += 32) {
        const bool more = (k0 + 32 < Kc);
        if (more) {                          // issue next-chunk global loads
            a0  = *(const float4*)(A + aoff + k0 + 32);
            a1  = *(const float4*)(A + aoff + k0 + 36);
            b00 = *(const float4*)(B + boff0 + k0 + 32);
            b01 = *(const float4*)(B + boff0 + k0 + 36);
            b10 = *(const float4*)(B + boff1 + k0 + 32);
            b11 = *(const float4*)(B + boff1 + k0 + 36);
        }
        __syncthreads();                     // buf[p] writes visible

        short8 ah[2], al[2], bh[4], bl[4];
        #pragma unroll
        for (int i = 0; i < 2; ++i) {
            ah[i] = *(const short8*)(&ldsA[p][0][wr * 32 + i * 16 + fr][fg * 8]);
            al[i] = *(const short8*)(&ldsA[p][1][wr * 32 + i * 16 + fr][fg * 8]);
        }
        #pragma unroll
        for (int j = 0; j < 4; ++j) {
            bh[j] = *(const short8*)(&ldsB[p][0][wc * 64 + j * 16 + fr][fg * 8]);
            bl[j] = *(const short8*)(&ldsB[p][1][wc * 64 + j * 16 + fr][fg * 8]);
        }
        #pragma unroll
        for (int i = 0; i < 2; ++i)
            #pragma unroll
            for (int j = 0; j < 4; ++j) {
                acc[i][j] = __builtin_amdgcn_mfma_f32_16x16x32_bf16(ah[i], bh[j], acc[i][j], 0, 0, 0);
                acc[i][j] = __builtin_amdgcn_mfma_f32_16x16x32_bf16(ah[i], bl[j], acc[i][j], 0, 0, 0);
                acc[i][j] = __builtin_amdgcn_mfma_f32_16x16x32_bf16(al[i], bh[j], acc[i][j], 0, 0, 0);
            }

        if (more) {                          // split + write next chunk to buf[p^1]
            short8 hs, ls;
            split8(a0, a1, hs, ls);
            *(short8*)(&ldsA[p ^ 1][0][srow][sg * 8]) = hs;
            *(short8*)(&ldsA[p ^ 1][1][srow][sg * 8]) = ls;
            split8(b00, b01, hs, ls);
            *(short8*)(&ldsB[p ^ 1][0][srow][sg * 8]) = hs;
            *(short8*)(&ldsB[p ^ 1][1][srow][sg * 8]) = ls;
            split8(b10, b11, hs, ls);
            *(short8*)(&ldsB[p ^ 1][0][64 + srow][sg * 8]) = hs;
            *(short8*)(&ldsB[p ^ 1][1][64 + srow][sg * 8]) = ls;
        }
        p ^= 1;
    }

    float* Cz = Cp + (size_t)kz * BDIM * KDIM;
    #pragma unroll
    for (int i = 0; i < 2; ++i)
        #pragma unroll
        for (int j = 0; j < 4; ++j)
            #pragma unroll
            for (int q = 0; q < 4; ++q) {
                int orow = bm * 64 + wr * 32 + i * 16 + (lane >> 4) * 4 + q;
                int ocol = bn * 128 + wc * 64 + j * 16 + (lane & 15);
                Cz[(size_t)orow * KDIM + ocol] = acc[i][j][q];
            }
}

// ---------------------------------------------------------------------------
// Fused reductions: blocks [0,512) = reduce Cp1 partials + norm + split;
// blocks [512,1536) = kn per pkeys row. (Frozen, bit-identical.)
// ---------------------------------------------------------------------------
__global__ __launch_bounds__(256)
void reduce_split_norm_kernel(const float* __restrict__ Cp,
                              const float* __restrict__ PK,
                              ushort* __restrict__ xh, ushort* __restrict__ xl,
                              float* __restrict__ xn, float* __restrict__ kn)
{
    const int blk = blockIdx.x, t = threadIdx.x;
    float sq;
    if (blk < BDIM) {
        const int b = blk;
        const int i = b * 256 + t;
        const int n4 = BDIM * KDIM / 4;

        float4 s = ((const float4*)Cp)[i];
        #pragma unroll
        for (int z = 1; z < 4; ++z) {
            float4 v = ((const float4*)Cp)[(size_t)z * n4 + i];
            s.x += v.x; s.y += v.y; s.z += v.z; s.w += v.w;
        }

        us4 h, l;
        h.x = f2bf_rn(s.x); l.x = f2bf_rn(s.x - bf2f(h.x));
        h.y = f2bf_rn(s.y); l.y = f2bf_rn(s.y - bf2f(h.y));
        h.z = f2bf_rn(s.z); l.z = f2bf_rn(s.z - bf2f(h.z));
        h.w = f2bf_rn(s.w); l.w = f2bf_rn(s.w - bf2f(h.w));
        ((us4*)xh)[i] = h;
        ((us4*)xl)[i] = l;

        sq = s.x * s.x + s.y * s.y + s.z * s.z + s.w * s.w;
    } else {
        const int m = blk - BDIM;
        float4 v = *(const float4*)(PK + (size_t)m * KDIM + t * 4);
        sq = v.x * v.x + v.y * v.y + v.z * v.z + v.w * v.w;
    }
    #pragma unroll
    for (int off = 32; off > 0; off >>= 1) sq += __shfl_down(sq, off, 64);
    __shared__ float wsum[4];
    const int lane = t & 63, wwid = t >> 6;
    if (lane == 0) wsum[wwid] = sq;
    __syncthreads();
    if (t == 0) {
        float r = sqrtf(wsum[0] + wsum[1] + wsum[2] + wsum[3]);
        if (blk < BDIM) xn[blk] = r; else kn[blk - BDIM] = r;
    }
}

// ---------------------------------------------------------------------------
// GEMM2 (sim partials): A pre-split, B = pkeys fp32 in-register split,
// 64x64 tile, dbuf LDS, split-K=2. (Frozen, bit-identical.)
// ---------------------------------------------------------------------------
__global__ __launch_bounds__(256)
void gemm2_kernel(const ushort* __restrict__ Ah, const ushort* __restrict__ Al,
                  const float* __restrict__ PK, float* __restrict__ Cp)
{
    __shared__ ushort lds[2][4][64][40];     // [buf][Ah/Al/Bh/Bl][row][col]

    const int t  = threadIdx.x;
    const int bn = blockIdx.x, bm = blockIdx.y, kz = blockIdx.z;
    const int srow = t >> 2, sg = t & 3;
    const int Kc = KDIM / 2;                 // 512

    const size_t aoff = (size_t)(bm * 64 + srow) * KDIM + kz * Kc + sg * 8;
    const size_t boff = (size_t)(bn * 64 + srow) * KDIM + kz * Kc + sg * 8;

    const int lane = t & 63, wid = t >> 6;
    const int wr = wid >> 1, wc = wid & 1;
    const int fr = lane & 15, fg = lane >> 4;

    f32x4 acc[2][2];
    #pragma unroll
    for (int i = 0; i < 2; ++i)
        #pragma unroll
        for (int j = 0; j < 2; ++j)
            acc[i][j] = (f32x4){0.f, 0.f, 0.f, 0.f};

    short8 pA0 = *(const short8*)(Ah + aoff);
    short8 pA1 = *(const short8*)(Al + aoff);
    float4 pb0 = *(const float4*)(PK + boff);
    float4 pb1 = *(const float4*)(PK + boff + 4);

    {
        short8 hs, ls;
        split8(pb0, pb1, hs, ls);
        *(short8*)(&lds[0][0][srow][sg * 8]) = pA0;
        *(short8*)(&lds[0][1][srow][sg * 8]) = pA1;
        *(short8*)(&lds[0][2][srow][sg * 8]) = hs;
        *(short8*)(&lds[0][3][srow][sg * 8]) = ls;
    }

    int p = 0;
    for (int k0 = 0; k0 < Kc; k0 += 32) {
        const bool more = (k0 + 32 < Kc);
        if (more) {
            pA0 = *(const short8*)(Ah + aoff + k0 + 32);
            pA1 = *(const short8*)(Al + aoff + k0 + 32);
            pb0 = *(const float4*)(PK + boff + k0 + 32);
            pb1 = *(const float4*)(PK + boff + k0 + 36);
        }
        __syncthreads();

        short8 ah[2], al[2], bh[2], bl[2];
        #pragma unroll
        for (int i = 0; i < 2; ++i) {
            ah[i] = *(const short8*)(&lds[p][0][wr * 32 + i * 16 + fr][fg * 8]);
            al[i] = *(const short8*)(&lds[p][1][wr * 32 + i * 16 + fr][fg * 8]);
            bh[i] = *(const short8*)(&lds[p][2][wc * 32 + i * 16 + fr][fg * 8]);
            bl[i] = *(const short8*)(&lds[p][3][wc * 32 + i * 16 + fr][fg * 8]);
        }
        #pragma unroll
        for (int i = 0; i < 2; ++i)
            #pragma unroll
            for (int j = 0; j < 2; ++j) {
                acc[i][j] = __builtin_amdgcn_mfma_f32_16x16x32_bf16(ah[i], bh[j], acc[i][j], 0, 0, 0);
                acc[i][j] = __builtin_amdgcn_mfma_f32_16x16x32_bf16(ah[i], bl[j], acc[i][j], 0, 0, 0);
                acc[i][j] = __builtin_amdgcn_mfma_f32_16x16x32_bf16(al[i], bh[j], acc[i][j], 0, 0, 0);
            }

        if (more) {
            short8 hs, ls;
            split8(pb0, pb1, hs, ls);
            *(short8*)(&lds[p ^ 1][0][srow][sg * 8]) = pA0;
            *(short8*)(&lds[p ^ 1][1][srow][sg * 8]) = pA1;
            *(short8*)(&lds[p ^ 1][2][srow][sg * 8]) = hs;
            *(short8*)(&lds[p ^ 1][3][srow][sg * 8]) = ls;
        }
        p ^= 1;
    }

    float* Cz = Cp + (size_t)kz * BDIM * MDIM;
    #pragma unroll
    for (int i = 0; i < 2; ++i)
        #pragma unroll
        for (int j = 0; j < 2; ++j)
            #pragma unroll
            for (int q = 0; q < 4; ++q) {
                int orow = bm * 64 + wr * 32 + i * 16 + (lane >> 4) * 4 + q;
                int ocol = bn * 64 + wc * 32 + j * 16 + (lane & 15);
                Cz[(size_t)orow * MDIM + ocol] = acc[i][j][q];
            }
}

// ---------------------------------------------------------------------------
// Fused reduce(2 partials) + cosine scale + top-4 + softmax weights.
// (Frozen, bit-identical.)
// ---------------------------------------------------------------------------
__device__ inline bool tk_better(float x, int ix, float y, int iy) {
    return (x > y) || (x == y && ix < iy);
}
__device__ inline void tk_insert(float (&v)[4], int (&id)[4], float x, int m) {
    if (tk_better(x, m, v[3], id[3])) {
        v[3] = x; id[3] = m;
        if (tk_better(v[3], id[3], v[2], id[2])) {
            float tv = v[2]; int ti = id[2]; v[2] = v[3]; id[2] = id[3]; v[3] = tv; id[3] = ti;
            if (tk_better(v[2], id[2], v[1], id[1])) {
                tv = v[1]; ti = id[1]; v[1] = v[2]; id[1] = id[2]; v[2] = tv; id[2] = ti;
                if (tk_better(v[1], id[1], v[0], id[0])) {
                    tv = v[0]; ti = id[0]; v[0] = v[1]; id[0] = id[1]; v[1] = tv; id[1] = ti;
                }
            }
        }
    }
}
__global__ __launch_bounds__(256)
void topk_scale_kernel(const float* __restrict__ Cp2, const float* __restrict__ xn,
                       const float* __restrict__ kn,
                       int* __restrict__ topi, float* __restrict__ topw)
{
    const int b = blockIdx.x, t = threadIdx.x;
    const int lane = t & 63, wid = t >> 6;
    const float sb = 1.f / fmaxf(xn[b], EPSF);
    const float* r0 = Cp2 + (size_t)b * MDIM;
    const float* r1 = Cp2 + (size_t)BDIM * MDIM + (size_t)b * MDIM;

    float v[4] = {-INFINITY, -INFINITY, -INFINITY, -INFINITY};
    int id[4] = {-1, -1, -1, -1};
    #pragma unroll
    for (int j = 0; j < MDIM / 256; ++j) {
        int m = wid * 256 + j * 64 + lane;
        float s = (r0[m] + r1[m]) * sb / fmaxf(kn[m], EPSF);
        tk_insert(v, id, s, m);
    }
    for (int off = 32; off >= 1; off >>= 1) {
        float pv[4]; int pi[4];
        #pragma unroll
        for (int q = 0; q < 4; ++q) {
            pv[q] = __shfl_xor(v[q], off, 64);
            pi[q] = __shfl_xor(id[q], off, 64);
        }
        #pragma unroll
        for (int q = 0; q < 4; ++q) tk_insert(v, id, pv[q], pi[q]);
    }

    __shared__ float sv[4][4];
    __shared__ int   si[4][4];
    if (lane == 0) {
        #pragma unroll
        for (int q = 0; q < 4; ++q) { sv[wid][q] = v[q]; si[wid][q] = id[q]; }
    }
    __syncthreads();
    if (t == 0) {
        float fv[4] = {-INFINITY, -INFINITY, -INFINITY, -INFINITY};
        int   fi[4] = {-1, -1, -1, -1};
        #pragma unroll
        for (int w = 0; w < 4; ++w)
            #pragma unroll
            for (int q = 0; q < 4; ++q)
                tk_insert(fv, fi, sv[w][q], si[w][q]);

        const float mx = fmaxf(fmaxf(fv[0], fv[1]), fmaxf(fv[2], fv[3]));
        const float e0 = expf(fv[0] - mx), e1 = expf(fv[1] - mx);
        const float e2 = expf(fv[2] - mx), e3 = expf(fv[3] - mx);
        const float inv = 1.f / (e0 + e1 + e2 + e3);
        topw[b * 4 + 0] = e0 * inv; topw[b * 4 + 1] = e1 * inv;
        topw[b * 4 + 2] = e2 * inv; topw[b * 4 + 3] = e3 * inv;
        #pragma unroll
        for (int q = 0; q < 4; ++q) topi[b * 4 + q] = fi[q];
    }
}

// ---------------------------------------------------------------------------
// Gather + weighted sum. (l, b)-major + non-temporal stores; fully unrolled.
// (Frozen, bit-identical; R10 proved block ordering is irrelevant — the
// l-slice is co-resident and L3 absorbs the reuse at ~8 TB/s effective.)
// ---------------------------------------------------------------------------
__global__ __launch_bounds__(256)
void gather_out_kernel(const float* __restrict__ pm, const int* __restrict__ topi,
                       const float* __restrict__ topw, float* __restrict__ out)
{
    const int bl = blockIdx.x;
    const int b = bl & (BDIM - 1);   // (l, b)-major
    const int l = bl >> 9;

    const int j0 = topi[b * 4 + 0], j1 = topi[b * 4 + 1], j2 = topi[b * 4 + 2], j3 = topi[b * 4 + 3];
    const float w0 = topw[b * 4 + 0], w1 = topw[b * 4 + 1], w2 = topw[b * 4 + 2], w3 = topw[b * 4 + 3];

    const f32x4* p0 = (const f32x4*)(pm + ((size_t)j0 * LDIM + l) * EDIM);
    const f32x4* p1 = (const f32x4*)(pm + ((size_t)j1 * LDIM + l) * EDIM);
    const f32x4* p2 = (const f32x4*)(pm + ((size_t)j2 * LDIM + l) * EDIM);
    const f32x4* p3 = (const f32x4*)(pm + ((size_t)j3 * LDIM + l) * EDIM);
    f32x4* o = (f32x4*)(out + ((size_t)b * LDIM + l) * EDIM);

    #pragma unroll
    for (int it = 0; it < EDIM / 4 / 256; ++it) {
        const int c = it * 256 + threadIdx.x;
        f32x4 a = p0[c], bb = p1[c], cc = p2[c], dd = p3[c];
        f32x4 r = w0 * a + w1 * bb + w2 * cc + w3 * dd;
        __builtin_nontemporal_store(r, &o[c]);
    }
}

extern "C" void kernel_launch(void* const* d_in, const int* in_sizes, int n_in,
                              void* d_out, int out_size, void* d_ws, size_t ws_size,
                              hipStream_t stream)
{
    const float* x_query = (const float*)d_in[0];      // [B, E]
    const float* W_proj  = (const float*)d_in[1];      // [K, E]
    const float* pm      = (const float*)d_in[2];      // [M, L, E]
    const float* pkeys   = (const float*)d_in[3];      // [M, K]
    float* out = (float*)d_out;                        // [B, L, E]

    // workspace layout
    char* w = (char*)d_ws;
    ushort* xp_h = (ushort*)w; w += (size_t)BDIM * KDIM * 2;
    ushort* xp_l = (ushort*)w; w += (size_t)BDIM * KDIM * 2;
    float* Cp1  = (float*)w; w += (size_t)4 * BDIM * KDIM * 4;   // 8 MB
    float* Cp2  = (float*)w; w += (size_t)2 * BDIM * MDIM * 4;   // 4 MB
    float* xn   = (float*)w; w += BDIM * 4;
    float* kn   = (float*)w; w += MDIM * 4;
    float* topw = (float*)w; w += BDIM * TOPK * 4;
    int*   topi = (int*)w;   w += BDIM * TOPK * 4;

    // 1. x_proj partials (fp32 inputs, in-register split, 64x128 dbuf, K=4)
    gemm1_kernel<<<dim3(KDIM / 128, BDIM / 64, 4), 256, 0, stream>>>(
        x_query, W_proj, Cp1);

    // 2. reduce + rownorm + split of x_proj  +  kn of pkeys rows
    reduce_split_norm_kernel<<<BDIM + MDIM, 256, 0, stream>>>(
        Cp1, pkeys, xp_h, xp_l, xn, kn);

    // 3. sim partials (A pre-split, B=pkeys fp32 in-register split, dbuf, K=2)
    gemm2_kernel<<<dim3(MDIM / 64, BDIM / 64, 2), 256, 0, stream>>>(
        xp_h, xp_l, pkeys, Cp2);

    // 4. reduce + cosine scale + top-4 + softmax weights (4 waves/row)
    topk_scale_kernel<<<BDIM, 256, 0, stream>>>(Cp2, xn, kn, topi, topw);

    // 5. gather + weighted sum -> out [512,32,4096]
    gather_out_kernel<<<BDIM * LDIM, 256, 0, stream>>>(pm, topi, topw, out);
}